// Round 1
// 461.307 us; speedup vs baseline: 1.0505x; 1.0505x over previous
//
#include <hip/hip_runtime.h>
#include <hip/hip_bf16.h>

// LatentSDE: y' = f_post(t,y) dt + sigma dW, f_post = MLP(2->512->512->1, tanh).
// Phase 1: tabulate f per (step, y-grid) via fused MFMA GEMM (68k rows x 512 x 512).
// Phase 1c: Catmull-Rom cubic coeffs per (step, cell).
// Phase 2: serial scan, one thread per batch elem. REWORKED this round:
//   - LDS ring (ds_write/ds_read, lgkm-coupled to vmcnt of C prefetch) DELETED.
//   - Table row lives in registers: lane l holds cell l's float4 (64 cells == 64 lanes).
//     Data-dependent gather via 4x ds_bpermute_b32 (crossbar, conflict-free, no
//     write in front of it on the lgkm queue).
//   - C rows: depth-8 register ring, coalesced global refill 8 steps ahead.
//   - dW: depth-16 register ring (was 8) -> latency floor ~56 cy/step.
//   - Chain surgery: t1 = fma(dw,0.5,yv) parallel to addr chain; split Horner
//     f = fma(s2, fma(s,cw,cz), fma(s,cy,cx)); explicit v_med3 clamp.

typedef __bf16 bf16x8 __attribute__((ext_vector_type(8)));
typedef float floatx4 __attribute__((ext_vector_type(4)));

#define NUM_STEPS 1000
#define BATCH 32768
#define HID 512
#define G_PTS 68             // stored y-grid points per step (64 cells + CR halo)
#define G_CELLS 64
#define P1_BLOCKS 1063       // * 64 rows = 68032 >= 1000*68
#define DT_F 0.001f
#define Y_LO (-4.0f)
#define DY 0.125f
#define INV_DY 8.0f

// tanh(x) = 1 - 2/(exp(2x)+1); saturates correctly for |x| large
__device__ __forceinline__ float tanh_fast(float x){
  float e = __expf(2.0f * x);
  return 1.0f - 2.0f / (e + 1.0f);
}

// ---------------- P0: W2 f32 [k][j] -> W2T bf16 [j][k] (512x512) ---------------
__global__ __launch_bounds__(256) void p0_transpose(const float* __restrict__ W2,
                                                    __bf16* __restrict__ W2T){
  int tid = blockIdx.x * 256 + threadIdx.x;
  #pragma unroll
  for (int r = 0; r < 4; ++r){
    int idx = tid + r * 65536;
    int a = idx >> 9, b = idx & 511;
    W2T[a * 512 + b] = (__bf16)W2[b * 512 + a];   // W2T[j][k] = W2[k][j]
  }
}

// ---------------- P1: h1 -> GEMM(W2) -> tanh -> dot(W3) => V[n*68+g] -----------
// Block: 256 thr = 4 waves, tile BM=64 rows x BN=512 (all cols), K-loop 32.
// MFMA 16x16x32 bf16. A: A[m=lane&15][k=quad*8+j]; B: B[k=quad*8+j][n=lane&15];
// C/D: col=lane&15, row=quad*4+reg (m89-verified).
__global__ __launch_bounds__(256, 2) void p1_gemm(
    const float* __restrict__ W1,
    const float* __restrict__ b1,
    const __bf16* __restrict__ W2T,
    const float* __restrict__ b2,
    const float* __restrict__ W3,
    const float* __restrict__ b3,
    float* __restrict__ V)
{
  __shared__ __align__(16) __bf16 Alds[64 * 40];    // 64 rows x 32 k, pad->40
  __shared__ __align__(16) __bf16 Blds[512 * 40];   // 512 cols x 32 k, pad->40
  __shared__ float red[4][64];

  const int tid  = threadIdx.x;
  const int bm   = blockIdx.x * 64;
  const int wave = tid >> 6;
  const int lane = tid & 63;
  const int quad = lane >> 4;
  const int l15  = lane & 15;

  // A-staging: 4 threads per row, each computes 8 h1 values per K-iter
  const int arow = tid >> 2;
  const int jb   = (tid & 3) * 8;
  const int r    = bm + arow;
  const int n    = r / G_PTS;
  const int g    = r - n * G_PTS;
  const float t  = (float)n * DT_F;
  const float yg = Y_LO + (float)(g - 1) * DY;   // halo point at g=0

  floatx4 acc[4][8];
  #pragma unroll
  for (int mt = 0; mt < 4; ++mt)
    #pragma unroll
    for (int nt = 0; nt < 8; ++nt){
      floatx4 z = {0.f, 0.f, 0.f, 0.f};
      acc[mt][nt] = z;
    }

  for (int kk = 0; kk < HID; kk += 32){
    // stage A: h1_j = tanh(t*W1[0,j] + y*W1[1,j] + b1[j]) for j = kk+jb..+7
    {
      const float* wt = W1 + kk + jb;          // row 0 of W1 (t weight)
      const float* wy = W1 + 512 + kk + jb;    // row 1 of W1 (y weight)
      const float* bp = b1 + kk + jb;
      bf16x8 hv;
      #pragma unroll
      for (int e = 0; e < 8; ++e){
        float z = fmaf(t, wt[e], fmaf(yg, wy[e], bp[e]));
        hv[e] = (__bf16)tanh_fast(z);
      }
      *reinterpret_cast<bf16x8*>(&Alds[arow * 40 + jb]) = hv;
    }
    // stage B: Blds[col][k] = W2T[col][kk+k]
    #pragma unroll
    for (int c8 = 0; c8 < 8; ++c8){
      int c = tid + c8 * 256;                  // 0..2047
      int nn = c >> 2, part = c & 3;
      bf16x8 v = *reinterpret_cast<const bf16x8*>(&W2T[nn * 512 + kk + part * 8]);
      *reinterpret_cast<bf16x8*>(&Blds[nn * 40 + part * 8]) = v;
    }
    __syncthreads();

    bf16x8 aF[4];
    #pragma unroll
    for (int mt = 0; mt < 4; ++mt)
      aF[mt] = *reinterpret_cast<const bf16x8*>(&Alds[(mt * 16 + l15) * 40 + quad * 8]);
    #pragma unroll
    for (int nt = 0; nt < 8; ++nt){
      bf16x8 bF = *reinterpret_cast<const bf16x8*>(&Blds[(wave * 128 + nt * 16 + l15) * 40 + quad * 8]);
      #pragma unroll
      for (int mt = 0; mt < 4; ++mt)
        acc[mt][nt] = __builtin_amdgcn_mfma_f32_16x16x32_bf16(aF[mt], bF, acc[mt][nt], 0, 0, 0);
    }
    __syncthreads();
  }

  // epilogue: V[row] = b3 + sum_k W3[k] * tanh(z[row][k] + b2[k])
  float p[4][4];
  #pragma unroll
  for (int mt = 0; mt < 4; ++mt)
    #pragma unroll
    for (int rg = 0; rg < 4; ++rg) p[mt][rg] = 0.f;

  #pragma unroll
  for (int nt = 0; nt < 8; ++nt){
    int col = wave * 128 + nt * 16 + l15;
    float b2v = b2[col];
    float w3v = W3[col];
    #pragma unroll
    for (int mt = 0; mt < 4; ++mt)
      #pragma unroll
      for (int rg = 0; rg < 4; ++rg)
        p[mt][rg] += tanh_fast(acc[mt][nt][rg] + b2v) * w3v;
  }
  #pragma unroll
  for (int off = 1; off < 16; off <<= 1)
    #pragma unroll
    for (int mt = 0; mt < 4; ++mt)
      #pragma unroll
      for (int rg = 0; rg < 4; ++rg)
        p[mt][rg] += __shfl_xor(p[mt][rg], off, 64);

  if (l15 == 0){
    #pragma unroll
    for (int mt = 0; mt < 4; ++mt)
      #pragma unroll
      for (int rg = 0; rg < 4; ++rg)
        red[wave][mt * 16 + quad * 4 + rg] = p[mt][rg];
  }
  __syncthreads();
  if (tid < 64){
    float s = red[0][tid] + red[1][tid] + red[2][tid] + red[3][tid] + b3[0];
    V[bm + tid] = s;
  }
}

// ---------------- P1c: Catmull-Rom coeffs per (step, cell) ---------------------
__global__ __launch_bounds__(256) void p1_coeff(const float* __restrict__ V,
                                                float4* __restrict__ C,
                                                float* __restrict__ sum_out){
  if (blockIdx.x == 0 && threadIdx.x == 0) sum_out[0] = 0.f;
  int cell = blockIdx.x * 256 + threadIdx.x;   // 64000 total
  int nn = cell >> 6;
  int j  = cell & 63;
  const float* v = &V[nn * G_PTS + j];
  float pm1 = v[0], p0 = v[1], p1 = v[2], p2 = v[3];
  float4 c;
  c.x = p0;
  c.y = 0.5f * (p1 - pm1);
  c.z = pm1 - 2.5f * p0 + 2.0f * p1 - 0.5f * p2;
  c.w = 1.5f * (p0 - p1) + 0.5f * (p2 - pm1);
  C[cell] = c;
}

// ---------------- P2: the serial scan, one thread per batch element ------------
// Per step: y -> (fma, med3, cvt, shl) -> 4x ds_bpermute gather of cell coeffs
// from the wave's registers -> split Horner -> y. No LDS data path at all.
__global__ __launch_bounds__(128) void p2_scan(
    const float* __restrict__ eps,
    const float* __restrict__ dW,
    const float* __restrict__ qm,
    const float* __restrict__ qlv,
    const float4* __restrict__ C,
    float* __restrict__ out,
    float* __restrict__ sum_out)
{
  __shared__ float wsum[2];
  const int tid  = threadIdx.x;
  const int w    = tid >> 6;
  const int lane = tid & 63;
  const int i    = blockIdx.x * 128 + tid;

  float qmean = qm[0];
  float qstd  = __expf(0.5f * qlv[0]);
  float yv = fmaf(eps[i], qstd, qmean);
  float acc2 = 0.f;
  float* orow = out + (size_t)i * NUM_STEPS;

  // register rings: cr[k&7] holds C row (step), lane l = cell l's float4;
  // dwr[k&15] holds dW for step k. Prefetch distances: C=8 steps, dW=16 steps.
  float4 cr[8];
  #pragma unroll
  for (int k = 0; k < 8; ++k) cr[k] = C[k * G_CELLS + lane];
  float dwr[16];
  #pragma unroll
  for (int k = 0; k < 16; ++k) dwr[k] = dW[k * BATCH + i];

  float4 ybuf = {0.f, 0.f, 0.f, 0.f};

#define SDE_STEP(ST, CS, DS, KP)                                              \
  {                                                                           \
    float u  = __builtin_amdgcn_fmed3f(fmaf(yv, INV_DY, 32.0f), 0.0f, 63.999f); \
    float t1 = fmaf(dwr[DS], 0.5f, yv);        /* parallel to addr chain */   \
    float q  = fmaf(2.0f, yv, -2.0f);          /* for Girsanov u, off-chain */\
    int   j  = (int)u;                                                        \
    int   j4 = j << 2;                                                        \
    float sf = u - (float)j;                                                  \
    int icx = __builtin_amdgcn_ds_bpermute(j4, __float_as_int(cr[CS].x));     \
    int icy = __builtin_amdgcn_ds_bpermute(j4, __float_as_int(cr[CS].y));     \
    int icz = __builtin_amdgcn_ds_bpermute(j4, __float_as_int(cr[CS].z));     \
    int icw = __builtin_amdgcn_ds_bpermute(j4, __float_as_int(cr[CS].w));     \
    float s2  = sf * sf;                       /* during gather latency */    \
    float tlo = fmaf(sf, __int_as_float(icy), __int_as_float(icx));           \
    float thi = fmaf(sf, __int_as_float(icw), __int_as_float(icz));           \
    float f   = fmaf(s2, thi, tlo);                                           \
    float uu  = fmaf(2.0f, f, q);                                             \
    acc2 = fmaf(uu, uu, acc2);                                                \
    yv = fmaf(f, DT_F, t1);                                                   \
    if      ((KP & 3) == 0) ybuf.x = yv;                                      \
    else if ((KP & 3) == 1) ybuf.y = yv;                                      \
    else if ((KP & 3) == 2) ybuf.z = yv;                                      \
    else { ybuf.w = yv; *reinterpret_cast<float4*>(orow + (ST) - 3) = ybuf; } \
    int nc = (ST) + 8;  nc = nc > 999 ? 999 : nc;                             \
    cr[CS] = C[nc * G_CELLS + lane];                                          \
    int nd = (ST) + 16; nd = nd > 999 ? 999 : nd;                             \
    dwr[DS] = dW[nd * BATCH + i];                                             \
  }

  for (int base = 0; base < 992; base += 16){
    #pragma unroll
    for (int k = 0; k < 16; ++k)
      SDE_STEP(base + k, (k & 7), k, k);
  }
  // tail: steps 992..999 (slots line up: s&7 = k, s&15 = k)
  #pragma unroll
  for (int k = 0; k < 8; ++k)
    SDE_STEP(992 + k, k, k, k);
#undef SDE_STEP

  float lq = 0.5f * DT_F * acc2;
  #pragma unroll
  for (int off = 1; off < 64; off <<= 1)
    lq += __shfl_xor(lq, off, 64);
  if (lane == 0) wsum[w] = lq;
  __syncthreads();
  if (tid == 0) atomicAdd(sum_out, wsum[0] + wsum[1]);
}

// ---------------- P3: kl0 + mean(logqp) -> out[last] ---------------------------
__global__ void p3_final(const float* __restrict__ qm,
                         const float* __restrict__ qlv,
                         const float* __restrict__ sum_in,
                         float* __restrict__ out){
  float qmean = qm[0];
  float qstd  = __expf(0.5f * qlv[0]);
  const float pstd = 0.35355339059327373f;        // sigma/sqrt(2*theta)
  float ratio = qstd / pstd;
  float dm = 1.0f - qmean;                        // MU - qy0_mean
  float kl0 = 0.5f * (ratio * ratio + (dm * dm) / (pstd * pstd)
                      - 1.0f + __logf(pstd / qstd));
  out[(size_t)BATCH * NUM_STEPS] = kl0 + sum_in[0] * (1.0f / 32768.0f);
}

extern "C" void kernel_launch(void* const* d_in, const int* in_sizes, int n_in,
                              void* d_out, int out_size, void* d_ws, size_t ws_size,
                              hipStream_t stream){
  const float* W1  = (const float*)d_in[0];
  const float* b1  = (const float*)d_in[1];
  const float* W2  = (const float*)d_in[2];
  const float* b2  = (const float*)d_in[3];
  const float* W3  = (const float*)d_in[4];
  const float* b3  = (const float*)d_in[5];
  const float* qm  = (const float*)d_in[6];
  const float* qlv = (const float*)d_in[7];
  const float* eps = (const float*)d_in[8];
  const float* dW  = (const float*)d_in[9];
  float* out = (float*)d_out;

  // workspace: W2T 512KB | V 272KB | C 1MB | sum
  char* ws = (char*)d_ws;
  __bf16* W2T = (__bf16*)(ws);
  float*  V   = (float*)(ws + 524288);
  float4* C   = (float4*)(ws + 796416);
  float*  sum = (float*)(ws + 1820416);

  p0_transpose<<<256, 256, 0, stream>>>(W2, W2T);
  p1_gemm<<<P1_BLOCKS, 256, 0, stream>>>(W1, b1, W2T, b2, W3, b3, V);
  p1_coeff<<<250, 256, 0, stream>>>(V, C, sum);
  p2_scan<<<BATCH / 128, 128, 0, stream>>>(eps, dW, qm, qlv, C, out, sum);
  p3_final<<<1, 1, 0, stream>>>(qm, qlv, sum, out);
}

// Round 3
// 431.543 us; speedup vs baseline: 1.1230x; 1.0690x over previous
//
#include <hip/hip_runtime.h>
#include <hip/hip_bf16.h>

// LatentSDE: y' = f_post(t,y) dt + sigma dW, f_post = MLP(2->512->512->1, tanh).
// Phase 1: tabulate f per (step, y-grid) via fused MFMA GEMM (68k rows x 512 x 512).
// Phase 1c: Catmull-Rom cubic coeffs per (step, cell).
// Phase 2: serial scan, one thread per batch elem. Round-2/3 rework:
//   - ALL global accesses forced to addrspace(1) (global_*, vmcnt-only) so the
//     per-step lgkmcnt(0) wait for bpermute covers ONLY bpermutes (no flat ops).
//     NOTE: values through addrspace(1) pointers must be ext_vector_type (clang
//     builtin), not HIP_vector_type — float4's copy-assign can't bind addrspace'd
//     references (round-2 compile failure).
//   - Refills burst-issued once per 16-step half-block into 32-deep register
//     rings (cr[32] floatx4, dwr[32]); sched_barrier(0) pins bursts before the
//     body. Body has zero vmem except the every-4-step output store; exactly
//     one vmcnt wait per 16 steps, statically satisfied (16-step prefetch).
//   - State in u-space (v = 8y+32): clamp/cvt/gather work directly on v; one
//     fewer fma on the chain; y-space conversions off-chain.

typedef __bf16 bf16x8 __attribute__((ext_vector_type(8)));
typedef float floatx4 __attribute__((ext_vector_type(4)));

#define NUM_STEPS 1000
#define BATCH 32768
#define HID 512
#define G_PTS 68             // stored y-grid points per step (64 cells + CR halo)
#define G_CELLS 64
#define P1_BLOCKS 1063       // * 64 rows = 68032 >= 1000*68
#define DT_F 0.001f
#define Y_LO (-4.0f)
#define DY 0.125f
#define INV_DY 8.0f

// force global (addrspace 1) memory ops — guarantees global_*, never flat_*
template <typename T>
__device__ __forceinline__ T gload(const T* p){
  return *(const T __attribute__((address_space(1)))*)((unsigned long long)p);
}
template <typename T>
__device__ __forceinline__ void gstore(T* p, T v){
  *(T __attribute__((address_space(1)))*)((unsigned long long)p) = v;
}

// tanh(x) = 1 - 2/(exp(2x)+1); saturates correctly for |x| large
__device__ __forceinline__ float tanh_fast(float x){
  float e = __expf(2.0f * x);
  return 1.0f - 2.0f / (e + 1.0f);
}

// ---------------- P0: W2 f32 [k][j] -> W2T bf16 [j][k] (512x512) ---------------
__global__ __launch_bounds__(256) void p0_transpose(const float* __restrict__ W2,
                                                    __bf16* __restrict__ W2T){
  int tid = blockIdx.x * 256 + threadIdx.x;
  #pragma unroll
  for (int r = 0; r < 4; ++r){
    int idx = tid + r * 65536;
    int a = idx >> 9, b = idx & 511;
    W2T[a * 512 + b] = (__bf16)W2[b * 512 + a];   // W2T[j][k] = W2[k][j]
  }
}

// ---------------- P1: h1 -> GEMM(W2) -> tanh -> dot(W3) => V[n*68+g] -----------
// Block: 256 thr = 4 waves, tile BM=64 rows x BN=512 (all cols), K-loop 32.
// MFMA 16x16x32 bf16. A: A[m=lane&15][k=quad*8+j]; B: B[k=quad*8+j][n=lane&15];
// C/D: col=lane&15, row=quad*4+reg (m89-verified).
__global__ __launch_bounds__(256, 2) void p1_gemm(
    const float* __restrict__ W1,
    const float* __restrict__ b1,
    const __bf16* __restrict__ W2T,
    const float* __restrict__ b2,
    const float* __restrict__ W3,
    const float* __restrict__ b3,
    float* __restrict__ V)
{
  __shared__ __align__(16) __bf16 Alds[64 * 40];    // 64 rows x 32 k, pad->40
  __shared__ __align__(16) __bf16 Blds[512 * 40];   // 512 cols x 32 k, pad->40
  __shared__ float red[4][64];

  const int tid  = threadIdx.x;
  const int bm   = blockIdx.x * 64;
  const int wave = tid >> 6;
  const int lane = tid & 63;
  const int quad = lane >> 4;
  const int l15  = lane & 15;

  // A-staging: 4 threads per row, each computes 8 h1 values per K-iter
  const int arow = tid >> 2;
  const int jb   = (tid & 3) * 8;
  const int r    = bm + arow;
  const int n    = r / G_PTS;
  const int g    = r - n * G_PTS;
  const float t  = (float)n * DT_F;
  const float yg = Y_LO + (float)(g - 1) * DY;   // halo point at g=0

  floatx4 acc[4][8];
  #pragma unroll
  for (int mt = 0; mt < 4; ++mt)
    #pragma unroll
    for (int nt = 0; nt < 8; ++nt){
      floatx4 z = {0.f, 0.f, 0.f, 0.f};
      acc[mt][nt] = z;
    }

  for (int kk = 0; kk < HID; kk += 32){
    // stage A: h1_j = tanh(t*W1[0,j] + y*W1[1,j] + b1[j]) for j = kk+jb..+7
    {
      const float* wt = W1 + kk + jb;          // row 0 of W1 (t weight)
      const float* wy = W1 + 512 + kk + jb;    // row 1 of W1 (y weight)
      const float* bp = b1 + kk + jb;
      bf16x8 hv;
      #pragma unroll
      for (int e = 0; e < 8; ++e){
        float z = fmaf(t, wt[e], fmaf(yg, wy[e], bp[e]));
        hv[e] = (__bf16)tanh_fast(z);
      }
      *reinterpret_cast<bf16x8*>(&Alds[arow * 40 + jb]) = hv;
    }
    // stage B: Blds[col][k] = W2T[col][kk+k]
    #pragma unroll
    for (int c8 = 0; c8 < 8; ++c8){
      int c = tid + c8 * 256;                  // 0..2047
      int nn = c >> 2, part = c & 3;
      bf16x8 v = *reinterpret_cast<const bf16x8*>(&W2T[nn * 512 + kk + part * 8]);
      *reinterpret_cast<bf16x8*>(&Blds[nn * 40 + part * 8]) = v;
    }
    __syncthreads();

    bf16x8 aF[4];
    #pragma unroll
    for (int mt = 0; mt < 4; ++mt)
      aF[mt] = *reinterpret_cast<const bf16x8*>(&Alds[(mt * 16 + l15) * 40 + quad * 8]);
    #pragma unroll
    for (int nt = 0; nt < 8; ++nt){
      bf16x8 bF = *reinterpret_cast<const bf16x8*>(&Blds[(wave * 128 + nt * 16 + l15) * 40 + quad * 8]);
      #pragma unroll
      for (int mt = 0; mt < 4; ++mt)
        acc[mt][nt] = __builtin_amdgcn_mfma_f32_16x16x32_bf16(aF[mt], bF, acc[mt][nt], 0, 0, 0);
    }
    __syncthreads();
  }

  // epilogue: V[row] = b3 + sum_k W3[k] * tanh(z[row][k] + b2[k])
  float p[4][4];
  #pragma unroll
  for (int mt = 0; mt < 4; ++mt)
    #pragma unroll
    for (int rg = 0; rg < 4; ++rg) p[mt][rg] = 0.f;

  #pragma unroll
  for (int nt = 0; nt < 8; ++nt){
    int col = wave * 128 + nt * 16 + l15;
    float b2v = b2[col];
    float w3v = W3[col];
    #pragma unroll
    for (int mt = 0; mt < 4; ++mt)
      #pragma unroll
      for (int rg = 0; rg < 4; ++rg)
        p[mt][rg] += tanh_fast(acc[mt][nt][rg] + b2v) * w3v;
  }
  #pragma unroll
  for (int off = 1; off < 16; off <<= 1)
    #pragma unroll
    for (int mt = 0; mt < 4; ++mt)
      #pragma unroll
      for (int rg = 0; rg < 4; ++rg)
        p[mt][rg] += __shfl_xor(p[mt][rg], off, 64);

  if (l15 == 0){
    #pragma unroll
    for (int mt = 0; mt < 4; ++mt)
      #pragma unroll
      for (int rg = 0; rg < 4; ++rg)
        red[wave][mt * 16 + quad * 4 + rg] = p[mt][rg];
  }
  __syncthreads();
  if (tid < 64){
    float s = red[0][tid] + red[1][tid] + red[2][tid] + red[3][tid] + b3[0];
    V[bm + tid] = s;
  }
}

// ---------------- P1c: Catmull-Rom coeffs per (step, cell) ---------------------
__global__ __launch_bounds__(256) void p1_coeff(const float* __restrict__ V,
                                                float4* __restrict__ C,
                                                float* __restrict__ sum_out){
  if (blockIdx.x == 0 && threadIdx.x == 0) sum_out[0] = 0.f;
  int cell = blockIdx.x * 256 + threadIdx.x;   // 64000 total
  int nn = cell >> 6;
  int j  = cell & 63;
  const float* v = &V[nn * G_PTS + j];
  float pm1 = v[0], p0 = v[1], p1 = v[2], p2 = v[3];
  float4 c;
  c.x = p0;
  c.y = 0.5f * (p1 - pm1);
  c.z = pm1 - 2.5f * p0 + 2.0f * p1 - 0.5f * p2;
  c.w = 1.5f * (p0 - p1) + 0.5f * (p2 - pm1);
  C[cell] = c;
}

// ---------------- P2: the serial scan, one thread per batch element ------------
// State v = 8y+32 (u-space). Per step: med3(v) -> cvt -> shl -> 4x ds_bpermute
// (gather from the wave's registers; lane l holds cell l) -> split Horner -> v.
// Refills burst per 16-step half-block; zero per-step vmem on the chain.
__global__ __launch_bounds__(128, 1) void p2_scan(
    const float* __restrict__ eps,
    const float* __restrict__ dW,
    const float* __restrict__ qm,
    const float* __restrict__ qlv,
    const float4* __restrict__ Cin,
    float* __restrict__ out,
    float* __restrict__ sum_out)
{
  __shared__ float wsum[2];
  const int tid  = threadIdx.x;
  const int w    = tid >> 6;
  const int lane = tid & 63;
  const int i    = blockIdx.x * 128 + tid;
  const floatx4* C = reinterpret_cast<const floatx4*>(Cin);

  float qmean = qm[0];
  float qstd  = __expf(0.5f * qlv[0]);
  float yv0 = fmaf(gload(eps + i), qstd, qmean);
  float vst = fmaf(yv0, 8.0f, 32.0f);      // u-space state
  float acc2 = 0.f;
  float* orow = out + (size_t)i * NUM_STEPS;

  // 32-deep register rings; slot = step & 31. Burst-refill 16 slots per
  // half-block, 16 steps ahead of use.
  floatx4 cr[32];
  float   dwr[32];
  #pragma unroll
  for (int k = 0; k < 16; ++k){
    cr[k]  = gload(C + k * G_CELLS + lane);
    dwr[k] = gload(dW + k * BATCH + i);
  }

  floatx4 ybuf = {0.f, 0.f, 0.f, 0.f};

#define REFILL(ROW, SL)                                                        \
  { int rr = (ROW) > 999 ? 999 : (ROW);                                        \
    cr[SL]  = gload(C + rr * G_CELLS + lane);                                  \
    dwr[SL] = gload(dW + rr * BATCH + i); }

#define SDE_STEP(ST, SL, KP)                                                   \
  {                                                                            \
    float u  = __builtin_amdgcn_fmed3f(vst, 0.0f, 63.999f);                    \
    float t1 = fmaf(dwr[SL], 4.0f, vst);       /* 0.5*dw in y == 4*dw in u */  \
    float q  = fmaf(vst, 0.25f, -10.0f);       /* 2y-2, off-chain */           \
    int   j  = (int)u;                                                         \
    int   j4 = j << 2;                                                         \
    float sf = u - (float)j;                                                   \
    int icx = __builtin_amdgcn_ds_bpermute(j4, __float_as_int(cr[SL][0]));     \
    int icy = __builtin_amdgcn_ds_bpermute(j4, __float_as_int(cr[SL][1]));     \
    int icz = __builtin_amdgcn_ds_bpermute(j4, __float_as_int(cr[SL][2]));     \
    int icw = __builtin_amdgcn_ds_bpermute(j4, __float_as_int(cr[SL][3]));     \
    float s2  = sf * sf;                       /* during gather latency */     \
    float tlo = fmaf(sf, __int_as_float(icy), __int_as_float(icx));            \
    float thi = fmaf(sf, __int_as_float(icw), __int_as_float(icz));            \
    float f   = fmaf(s2, thi, tlo);                                            \
    float uu  = fmaf(2.0f, f, q);                                              \
    acc2 = fmaf(uu, uu, acc2);                                                 \
    vst = fmaf(f, 8.0f * DT_F, t1);            /* exact 8x of y-space step */  \
    float yo = fmaf(vst, 0.125f, -4.0f);       /* back to y, off-chain */      \
    if      ((KP & 3) == 0) ybuf[0] = yo;                                      \
    else if ((KP & 3) == 1) ybuf[1] = yo;                                      \
    else if ((KP & 3) == 2) ybuf[2] = yo;                                      \
    else { ybuf[3] = yo;                                                       \
           gstore(reinterpret_cast<floatx4*>(orow + (ST) - 3), ybuf); }        \
  }

  for (int b2 = 0; b2 < 992; b2 += 32){
    // topA: issue rows b2+16..b2+31 into slots 16..31 (used 16 steps later)
    #pragma unroll
    for (int k = 0; k < 16; ++k) REFILL(b2 + 16 + k, 16 + k);
    __builtin_amdgcn_sched_barrier(0);
    // bodyA: steps b2..b2+15 from slots 0..15 (loaded 16 steps ago)
    #pragma unroll
    for (int k = 0; k < 16; ++k) SDE_STEP(b2 + k, k, k);
    // topB: issue rows b2+32..b2+47 into slots 0..15
    #pragma unroll
    for (int k = 0; k < 16; ++k) REFILL(b2 + 32 + k, k);
    __builtin_amdgcn_sched_barrier(0);
    // bodyB: steps b2+16..b2+31 from slots 16..31
    #pragma unroll
    for (int k = 0; k < 16; ++k) SDE_STEP(b2 + 16 + k, 16 + k, k);
  }
  // tail: steps 992..999, slots 0..7 (refilled at last topB)
  #pragma unroll
  for (int k = 0; k < 8; ++k) SDE_STEP(992 + k, k, k);
#undef SDE_STEP
#undef REFILL

  float lq = 0.5f * DT_F * acc2;
  #pragma unroll
  for (int off = 1; off < 64; off <<= 1)
    lq += __shfl_xor(lq, off, 64);
  if (lane == 0) wsum[w] = lq;
  __syncthreads();
  if (tid == 0) atomicAdd(sum_out, wsum[0] + wsum[1]);
}

// ---------------- P3: kl0 + mean(logqp) -> out[last] ---------------------------
__global__ void p3_final(const float* __restrict__ qm,
                         const float* __restrict__ qlv,
                         const float* __restrict__ sum_in,
                         float* __restrict__ out){
  float qmean = qm[0];
  float qstd  = __expf(0.5f * qlv[0]);
  const float pstd = 0.35355339059327373f;        // sigma/sqrt(2*theta)
  float ratio = qstd / pstd;
  float dm = 1.0f - qmean;                        // MU - qy0_mean
  float kl0 = 0.5f * (ratio * ratio + (dm * dm) / (pstd * pstd)
                      - 1.0f + __logf(pstd / qstd));
  out[(size_t)BATCH * NUM_STEPS] = kl0 + sum_in[0] * (1.0f / 32768.0f);
}

extern "C" void kernel_launch(void* const* d_in, const int* in_sizes, int n_in,
                              void* d_out, int out_size, void* d_ws, size_t ws_size,
                              hipStream_t stream){
  const float* W1  = (const float*)d_in[0];
  const float* b1  = (const float*)d_in[1];
  const float* W2  = (const float*)d_in[2];
  const float* b2  = (const float*)d_in[3];
  const float* W3  = (const float*)d_in[4];
  const float* b3  = (const float*)d_in[5];
  const float* qm  = (const float*)d_in[6];
  const float* qlv = (const float*)d_in[7];
  const float* eps = (const float*)d_in[8];
  const float* dW  = (const float*)d_in[9];
  float* out = (float*)d_out;

  // workspace: W2T 512KB | V 272KB | C 1MB | sum
  char* ws = (char*)d_ws;
  __bf16* W2T = (__bf16*)(ws);
  float*  V   = (float*)(ws + 524288);
  float4* C   = (float4*)(ws + 796416);
  float*  sum = (float*)(ws + 1820416);

  p0_transpose<<<256, 256, 0, stream>>>(W2, W2T);
  p1_gemm<<<P1_BLOCKS, 256, 0, stream>>>(W1, b1, W2T, b2, W3, b3, V);
  p1_coeff<<<250, 256, 0, stream>>>(V, C, sum);
  p2_scan<<<BATCH / 128, 128, 0, stream>>>(eps, dW, qm, qlv, C, out, sum);
  p3_final<<<1, 1, 0, stream>>>(qm, qlv, sum, out);
}